// Round 2
// baseline (7826.683 us; speedup 1.0000x reference)
//
#include <hip/hip_runtime.h>
#include <stdint.h>

// ---------------------------------------------------------------------------
// Net_57604101374728: GCN(x3)+BN -> maxpool | 6x belief-prop -> diffpool ->
// dense GCN(x3)+BN -> maxpool -> FC. Full fp32 port of the JAX reference.
//
// R2: BP restructured thread-per-row with compile-time Q, per-run [NN][Q]
// psi layout (vectorized gathers), XCD-aware block mapping, RNG fused into
// first step. k_gcn_agg / k_T also vectorized. FP operation ORDER preserved
// bit-for-bit vs R1 (which measured absmax 0.0).
// ---------------------------------------------------------------------------

constexpr int NN    = 65536;    // total nodes
constexpr int NEDGE = 524288;   // edges
constexpr int NBG   = 64;       // graphs

__constant__ int cQS[6]   = {2,4,8,16,32,64};
__constant__ int cQOFF[6] = {0,2,6,14,30,62};

// ---------------- threefry2x32 (20 rounds) ----------------
__device__ __forceinline__ void tf2x32(uint32_t k0, uint32_t k1, uint32_t x0, uint32_t x1,
                                       uint32_t& o0, uint32_t& o1){
  uint32_t ks[3] = {k0, k1, k0 ^ k1 ^ 0x1BD11BDAu};
  x0 += ks[0]; x1 += ks[1];
  const int RA[4] = {13,15,26,6}, RB[4] = {17,29,16,24};
  #pragma unroll
  for (int i=0;i<5;i++){
    const int* r = (i&1)? RB : RA;
    #pragma unroll
    for (int j=0;j<4;j++){
      x0 += x1;
      x1 = (x1 << r[j]) | (x1 >> (32 - r[j]));
      x1 ^= x0;
    }
    x0 += ks[(i+1)%3];
    x1 += ks[(i+2)%3] + (uint32_t)(i+1);
  }
  o0 = x0; o1 = x1;
}

// ---------------- XLA ErfInv32 (Giles), contraction off ----------------
__device__ __forceinline__ float erfinv32(float xx){
  #pragma clang fp contract(off)
  float w = -log1pf(-xx*xx);
  float p;
  if (w < 5.0f){
    w = w - 2.5f;
    p = 2.81022636e-08f;
    p = 3.43273939e-07f  + p*w;
    p = -3.5233877e-06f  + p*w;
    p = -4.39150654e-06f + p*w;
    p = 0.00021858087f   + p*w;
    p = -0.00125372503f  + p*w;
    p = -0.00417768164f  + p*w;
    p = 0.246640727f     + p*w;
    p = 1.50140941f      + p*w;
  } else {
    w = sqrtf(w) - 3.0f;
    p = -0.000200214257f;
    p = 0.000100950558f  + p*w;
    p = 0.00134934322f   + p*w;
    p = -0.00367342844f  + p*w;
    p = 0.00573950773f   + p*w;
    p = -0.0076224613f   + p*w;
    p = 0.00943887047f   + p*w;
    p = 1.00167406f      + p*w;
    p = 2.83297682f      + p*w;
  }
  return p*xx;
}

// ---------------- CSR construction ----------------
__global__ __launch_bounds__(256) void k_count(const int* __restrict__ src, const int* __restrict__ dst,
                                               int* __restrict__ degi, int* __restrict__ dego){
  int e = blockIdx.x*256 + threadIdx.x;
  if (e >= NEDGE) return;
  atomicAdd(&degi[dst[e]], 1);
  atomicAdd(&dego[src[e]], 1);
}

__global__ __launch_bounds__(256) void k_scan1(const int* __restrict__ deg, int* __restrict__ rp,
                                               int* __restrict__ bsum){
  __shared__ int lds[256];
  int b = blockIdx.x, t = threadIdx.x;
  lds[t] = deg[b*256 + t];
  __syncthreads();
  for (int s=1;s<256;s<<=1){
    int add = (t>=s)? lds[t-s] : 0;
    __syncthreads();
    lds[t] += add;
    __syncthreads();
  }
  rp[b*256 + t + 1] = lds[t];
  if (t==0 && b==0) rp[0] = 0;
  if (t==255) bsum[b] = lds[255];
}

__global__ __launch_bounds__(256) void k_scan2(int* __restrict__ bsum){
  __shared__ int lds[256];
  int t = threadIdx.x;
  lds[t] = bsum[t];
  __syncthreads();
  for (int s=1;s<256;s<<=1){
    int add = (t>=s)? lds[t-s] : 0;
    __syncthreads();
    lds[t] += add;
    __syncthreads();
  }
  bsum[t] = (t==0)? 0 : lds[t-1];
}

__global__ __launch_bounds__(256) void k_scan3(int* __restrict__ rp, const int* __restrict__ bsum){
  int b = blockIdx.x, t = threadIdx.x;
  rp[b*256 + t + 1] += bsum[b];
}

__global__ __launch_bounds__(256) void k_fill(const int* __restrict__ key, const int* __restrict__ rp,
                                              int* __restrict__ cnt, int* __restrict__ colbuf){
  int e = blockIdx.x*256 + threadIdx.x;
  if (e >= NEDGE) return;
  int d = key[e];
  int p = atomicAdd(&cnt[d], 1);
  colbuf[rp[d] + p] = e;             // store edge id (sorted next for determinism)
}

__global__ __launch_bounds__(256) void k_sortrow(const int* __restrict__ rp, int* __restrict__ colbuf,
                                                 const int* __restrict__ other){
  int v = blockIdx.x*256 + threadIdx.x;
  if (v >= NN) return;
  int s0 = rp[v], s1 = rp[v+1];
  for (int i=s0+1;i<s1;i++){         // insertion sort by edge id ascending
    int key = colbuf[i]; int j = i-1;
    while (j>=s0 && colbuf[j]>key){ colbuf[j+1]=colbuf[j]; j--; }
    colbuf[j+1] = key;
  }
  for (int i=s0;i<s1;i++) colbuf[i] = other[colbuf[i]];
}

__global__ __launch_bounds__(256) void k_dinv(const int* __restrict__ degi, float* __restrict__ dinv){
  int v = blockIdx.x*256 + threadIdx.x;
  if (v >= NN) return;
  dinv[v] = 1.0f / sqrtf((float)(degi[v] + 1));   // +1 for self loop
}

// ---------------- stage-1 GCN ----------------
template<int CIN>
__global__ __launch_bounds__(256) void k_mm30(const float* __restrict__ x, const float* __restrict__ w,
                                              float* __restrict__ h, int nrow){
  __shared__ float ws[CIN*30];
  int t = threadIdx.x;
  for (int i=t;i<CIN*30;i+=256) ws[i] = w[i];
  __syncthreads();
  int id = blockIdx.x*256 + t;
  if (id >= nrow*30) return;
  int v = id/30, j = id - v*30;
  const float* xr = x + v*CIN;
  float acc = 0.f;
  #pragma unroll
  for (int k=0;k<CIN;k++) acc += xr[k]*ws[k*30+j];
  h[id] = acc;
}

// thread-per-row, 30 cols in registers, float2 gathers; FP order == R1
__global__ __launch_bounds__(256) void k_gcn_agg(const float* __restrict__ h, const int* __restrict__ rp,
    const int* __restrict__ col, const float* __restrict__ dinv, const float* __restrict__ bias,
    float* __restrict__ y){
  int b = blockIdx.x;              // 256 blocks
  int xcd = b & 7, j = b >> 3;     // graph -> fixed XCD bucket
  int row = (xcd*8 + (j>>2))*1024 + (j&3)*256 + threadIdx.x;
  float dv = dinv[row];
  float acc[30];
  #pragma unroll
  for (int c=0;c<30;c++) acc[c] = 0.f;
  int a = rp[row], e = rp[row+1];
  for (int i=a;i<e;i++){
    int s = col[i];
    float w = dinv[s]*dv;
    const float2* p = reinterpret_cast<const float2*>(h + s*30);
    #pragma unroll
    for (int k=0;k<15;k++){
      float2 t = p[k];
      acc[2*k]   += t.x*w;
      acc[2*k+1] += t.y*w;
    }
  }
  const float* hr = h + row*30;
  float w2 = dv*dv;
  #pragma unroll
  for (int c=0;c<30;c++) acc[c] += hr[c]*w2;     // self loop last (JAX concat order)
  float2* o = reinterpret_cast<float2*>(y + row*30);
  #pragma unroll
  for (int k=0;k<15;k++) o[k] = make_float2(acc[2*k]+bias[2*k], acc[2*k+1]+bias[2*k+1]);
}

// ---------------- BatchNorm (two-pass, biased var) ----------------
__global__ __launch_bounds__(256) void k_bn_part(const float* __restrict__ x, int nrow,
    const float* __restrict__ mean, int pass, float* __restrict__ part){
  __shared__ float lds[256*31];
  int b = blockIdx.x, t = threadIdx.x;
  int rows = nrow >> 8;              // rows per block (nrow divisible by 256)
  float acc[30];
  #pragma unroll
  for (int f=0;f<30;f++) acc[f] = 0.f;
  for (int r=t; r<rows; r+=256){
    const float* xr = x + (b*rows + r)*30;
    if (pass == 0){
      #pragma unroll
      for (int f=0;f<30;f++) acc[f] += xr[f];
    } else {
      #pragma unroll
      for (int f=0;f<30;f++){ float d = xr[f]-mean[f]; acc[f] += d*d; }
    }
  }
  #pragma unroll
  for (int f=0;f<30;f++) lds[t*31+f] = acc[f];
  __syncthreads();
  for (int s=128;s>0;s>>=1){
    if (t<s){
      #pragma unroll
      for (int f=0;f<30;f++) lds[t*31+f] += lds[(t+s)*31+f];
    }
    __syncthreads();
  }
  if (t<30) part[b*30+t] = lds[t];
}

__global__ void k_bn_red(const float* __restrict__ part, float n, float* __restrict__ out){
  int f = threadIdx.x;
  if (f >= 30) return;
  float s = 0.f;
  for (int b=0;b<256;b++) s += part[b*30+f];
  out[f] = s / n;
}

__global__ __launch_bounds__(256) void k_bn_apply(const float* __restrict__ x, const float* __restrict__ mean,
    const float* __restrict__ var, const float* __restrict__ g, const float* __restrict__ be,
    float* __restrict__ out, int nrow){
  int id = blockIdx.x*256 + threadIdx.x;
  if (id >= nrow*30) return;
  int f = id % 30;
  out[id] = g[f]*(x[id]-mean[f]) * (1.0f/sqrtf(var[f]+1e-5f)) + be[f];
}

// ---------------- belief propagation (thread-per-row, reg softmax) ----------------
// butterfly emulation == R1's __shfl_xor sequence, bit-identical
template<int Q>
__device__ __forceinline__ void softmax_bfly(const float* v, float* outp, const float inv_dummy=0.f){
  float m[Q];
  #pragma unroll
  for (int c=0;c<Q;c++) m[c] = v[c];
  #pragma unroll
  for (int off=Q>>1; off; off>>=1){
    float t[Q];
    #pragma unroll
    for (int c=0;c<Q;c++) t[c] = fmaxf(m[c], m[c^off]);
    #pragma unroll
    for (int c=0;c<Q;c++) m[c] = t[c];
  }
  float mm = m[0];                       // all equal bits
  float e[Q];
  #pragma unroll
  for (int c=0;c<Q;c++) e[c] = expf(v[c]-mm);
  float ss[Q];
  #pragma unroll
  for (int c=0;c<Q;c++) ss[c] = e[c];
  #pragma unroll
  for (int off=Q>>1; off; off>>=1){
    float t[Q];
    #pragma unroll
    for (int c=0;c<Q;c++) t[c] = ss[c] + ss[c^off];
    #pragma unroll
    for (int c=0;c<Q;c++) ss[c] = t[c];
  }
  float s0 = ss[0];                      // all equal bits
  #pragma unroll
  for (int c=0;c<Q;c++) outp[c] = e[c]/s0;
}

template<int Q>
__device__ __forceinline__ void bp_store(float* __restrict__ dstRun, int row, const float* r){
  if constexpr (Q==2){
    *reinterpret_cast<float2*>(dstRun + row*2) = make_float2(r[0], r[1]);
  } else {
    float4* o = reinterpret_cast<float4*>(dstRun + (size_t)row*Q);
    #pragma unroll
    for (int k=0;k<Q/4;k++) o[k] = make_float4(r[4*k], r[4*k+1], r[4*k+2], r[4*k+3]);
  }
}

// first step: generate psi0 (threefry+erfinv) and softmax it, in registers
template<int Q, int QO>
__device__ __forceinline__ void bp_first_row(int row, int run, float* __restrict__ psiOut){
  uint32_t k0, k1;
  tf2x32(0u, 42u, 0u, (uint32_t)run, k0, k1);          // fold_in(key(42), run)
  float z[Q];
  #pragma unroll
  for (int c=0;c<Q;c++){
    uint32_t b0, b1;
    tf2x32(k0, k1, 0u, (uint32_t)(row*Q + c), b0, b1); // counter = (0, idx)
    uint32_t bits = b0 ^ b1;
    float f = __uint_as_float((bits>>9) | 0x3F800000u) - 1.0f;   // [0,1)
    const float lo = __uint_as_float(0xBF7FFFFFu);               // nextafter(-1,0)
    float u = fmaxf(lo, f*2.0f + lo);
    z[c] = __uint_as_float(0x3FB504F3u) * erfinv32(u);           // sqrt(2)*erfinv
  }
  float r[Q];
  softmax_bfly<Q>(z, r);
  bp_store<Q>(psiOut + (size_t)NN*QO, row, r);
}

template<int Q, int QO>
__device__ __forceinline__ void bp_step_row(int row, int run, const float* __restrict__ psiIn,
    float* __restrict__ psiOut, float* __restrict__ outF,
    const int* __restrict__ rp, const int* __restrict__ col,
    const float* __restrict__ field, float beta, int finalIter){
  const float* cur = psiIn + (size_t)NN*QO;
  float eb = expm1f(beta);
  float acc[Q];
  #pragma unroll
  for (int c=0;c<Q;c++) acc[c] = 0.f;
  int a = rp[row], b2 = rp[row+1];
  for (int i=a;i<b2;i++){
    int s = col[i];
    if constexpr (Q==2){
      float2 t = *reinterpret_cast<const float2*>(cur + s*2);
      acc[0] += log1pf(eb*t.x);
      acc[1] += log1pf(eb*t.y);
    } else {
      const float4* p = reinterpret_cast<const float4*>(cur + (size_t)s*Q);
      #pragma unroll
      for (int k=0;k<Q/4;k++){
        float4 t = p[k];
        acc[4*k+0] += log1pf(eb*t.x);
        acc[4*k+1] += log1pf(eb*t.y);
        acc[4*k+2] += log1pf(eb*t.z);
        acc[4*k+3] += log1pf(eb*t.w);
      }
    }
  }
  #pragma unroll
  for (int c=0;c<Q;c++) acc[c] -= field[run*64 + c];
  float r[Q];
  softmax_bfly<Q>(acc, r);
  if (finalIter){
    float* o = outF + (size_t)row*126 + QO + (QO==0?0:0);   // concat layout col offset
    // NOTE: QO is the run's column offset in the 126-concat (cQOFF), which for
    // per-run layout we reused as NN-offset multiplier; both use the same value.
    #pragma unroll
    for (int c=0;c<Q;c++) o[c] = r[c];
  } else {
    bp_store<Q>(psiOut + (size_t)NN*QO, row, r);
  }
}

__global__ __launch_bounds__(256) void k_bp_first(float* __restrict__ psiOut){
  int b = blockIdx.x;                       // 1536 blocks
  int xcd = b & 7, j = b >> 3;              // xcd-major: graphs grouped per XCD
  int gg = j/24, jj = j - gg*24;
  int run = jj >> 2, chunk = jj & 3;
  int row = (xcd*8 + gg)*1024 + chunk*256 + threadIdx.x;
  switch(run){
    case 0: bp_first_row< 2, 0>(row, 0, psiOut); break;
    case 1: bp_first_row< 4, 2>(row, 1, psiOut); break;
    case 2: bp_first_row< 8, 6>(row, 2, psiOut); break;
    case 3: bp_first_row<16,14>(row, 3, psiOut); break;
    case 4: bp_first_row<32,30>(row, 4, psiOut); break;
    default: bp_first_row<64,62>(row, 5, psiOut); break;
  }
}

__global__ __launch_bounds__(256) void k_bp_step(const float* __restrict__ psiIn,
    float* __restrict__ psiOut, float* __restrict__ outF,
    const int* __restrict__ rp, const int* __restrict__ col,
    const float* __restrict__ field, const float* __restrict__ betas, int finalIter){
  int b = blockIdx.x;
  int xcd = b & 7, j = b >> 3;
  int gg = j/24, jj = j - gg*24;
  int run = jj >> 2, chunk = jj & 3;
  int row = (xcd*8 + gg)*1024 + chunk*256 + threadIdx.x;
  float beta = betas[run];
  switch(run){
    case 0: bp_step_row< 2, 0>(row, 0, psiIn, psiOut, outF, rp, col, field, beta, finalIter); break;
    case 1: bp_step_row< 4, 2>(row, 1, psiIn, psiOut, outF, rp, col, field, beta, finalIter); break;
    case 2: bp_step_row< 8, 6>(row, 2, psiIn, psiOut, outF, rp, col, field, beta, finalIter); break;
    case 3: bp_step_row<16,14>(row, 3, psiIn, psiOut, outF, rp, col, field, beta, finalIter); break;
    case 4: bp_step_row<32,30>(row, 4, psiIn, psiOut, outF, rp, col, field, beta, finalIter); break;
    default: bp_step_row<64,62>(row, 5, psiIn, psiOut, outF, rp, col, field, beta, finalIter); break;
  }
}

// column sums over per-run [NN][Q] layout; value ORDER identical to R1
__global__ __launch_bounds__(64) void k_colsum_part(const float* __restrict__ psi, float* __restrict__ part){
  int run = blockIdx.y, q = cQS[run], qo = cQOFF[run];
  int b = blockIdx.x, c = threadIdx.x;
  if (c >= q) return;
  float s = 0.f;
  const float* p = psi + (size_t)NN*qo + (size_t)b*256*q + c;
  for (int r=0;r<256;r++) s += p[r*q];
  part[(run*256 + b)*64 + c] = s;
}

__global__ void k_field(const float* __restrict__ part, const float* __restrict__ betas,
                        float* __restrict__ field){
  int id = threadIdx.x;              // 384 threads: 6 runs x 64 cols
  int run = id >> 6, c = id & 63;
  if (c >= cQS[run]) return;
  float s = 0.f;
  for (int b=0;b<256;b++) s += part[(run*256 + b)*64 + c];
  float beta = betas[run];
  field[id] = s * (3.8f*beta/65536.0f);
}

// ---------------- diff-pool ----------------
__global__ __launch_bounds__(256) void k_s1(const float* __restrict__ cat, const float* __restrict__ pw,
                                            const float* __restrict__ pb, float* __restrict__ s1){
  __shared__ float wl[12600];
  __shared__ float rowb[2][126];
  __shared__ float red[8];
  int t = threadIdx.x;
  for (int i=t;i<12600;i+=256) wl[i] = pw[i];
  int half = t>>7, tl = t&127, wid = t>>6;
  __syncthreads();
  for (int it=0; it<16; ++it){
    int v = blockIdx.x*32 + it*2 + half;
    if (tl < 126) rowb[half][tl] = cat[v*126 + tl];
    __syncthreads();
    float acc = -3.402823466e38f;
    if (tl < 100){
      acc = pb[tl];
      for (int j=0;j<126;j++) acc += rowb[half][j]*wl[j*100+tl];
    }
    float m = acc;
    for (int off=32; off; off>>=1) m = fmaxf(m, __shfl_xor(m, off, 64));
    if ((t&63)==0) red[wid] = m;
    __syncthreads();
    m = fmaxf(red[half*2], red[half*2+1]);
    float e = (tl<100)? expf(acc - m) : 0.f;
    float ss = e;
    for (int off=32; off; off>>=1) ss += __shfl_xor(ss, off, 64);
    if ((t&63)==0) red[4+wid] = ss;
    __syncthreads();
    float stot = red[4+half*2] + red[4+half*2+1];
    if (tl<100) s1[v*100+tl] = e/stot;
    __syncthreads();
  }
}

// thread-per-row, 100 cols in registers, float4 gathers; FP order == R1
__global__ __launch_bounds__(256) void k_T(const float* __restrict__ s1, const int* __restrict__ rp,
                                           const int* __restrict__ col, float* __restrict__ T){
  int b = blockIdx.x;              // 256 blocks
  int xcd = b & 7, j = b >> 3;
  int row = (xcd*8 + (j>>2))*1024 + (j&3)*256 + threadIdx.x;
  float acc[100];
  #pragma unroll
  for (int c=0;c<100;c++) acc[c] = 0.f;
  int a = rp[row], e = rp[row+1];
  for (int i=a;i<e;i++){
    int s = col[i];
    const float4* p = reinterpret_cast<const float4*>(s1 + (size_t)s*100);
    #pragma unroll
    for (int k=0;k<25;k++){
      float4 t = p[k];
      acc[4*k+0] += t.x;
      acc[4*k+1] += t.y;
      acc[4*k+2] += t.z;
      acc[4*k+3] += t.w;
    }
  }
  float4* o = reinterpret_cast<float4*>(T + (size_t)row*100);
  #pragma unroll
  for (int k=0;k<25;k++) o[k] = make_float4(acc[4*k], acc[4*k+1], acc[4*k+2], acc[4*k+3]);
}

__global__ __launch_bounds__(128) void k_p1adj(const float* __restrict__ s1, const float* __restrict__ T,
                                               float* __restrict__ padj){
  int b  = blockIdx.x/25;
  int k0 = (blockIdx.x%25)*4;
  int l  = threadIdx.x;
  const float* s1b = s1 + b*1024*100;
  const float* Tb  = T  + b*1024*100;
  float a0=0.f,a1=0.f,a2=0.f,a3=0.f;
  for (int n=0;n<1024;n++){
    float tv = (l<100)? Tb[n*100+l] : 0.f;
    const float* sr = s1b + n*100 + k0;
    a0 += sr[0]*tv; a1 += sr[1]*tv; a2 += sr[2]*tv; a3 += sr[3]*tv;
  }
  if (l<100){
    float* o = padj + b*10000 + k0*100 + l;
    o[0]=a0; o[100]=a1; o[200]=a2; o[300]=a3;
  }
}

__global__ __launch_bounds__(128) void k_p1x(const float* __restrict__ s1, const float* __restrict__ x13,
                                             float* __restrict__ px){
  int b  = blockIdx.x/25;
  int k0 = (blockIdx.x%25)*4;
  int t = threadIdx.x;
  int j = t>>5, d = t&31;
  float acc = 0.f;
  for (int n=0;n<1024;n++){
    float xv = (d<30)? x13[(b*1024+n)*30 + d] : 0.f;
    acc += s1[(b*1024+n)*100 + k0 + j]*xv;
  }
  if (d<30) px[(b*100 + k0 + j)*30 + d] = acc;
}

// ---------------- stage-2 dense GCN ----------------
__global__ __launch_bounds__(256) void k_dinv2(const float* __restrict__ padj, float* __restrict__ dv){
  int id = blockIdx.x*256 + threadIdx.x;
  if (id >= NBG*100) return;
  const float* r = padj + id*100;
  int k = id % 100;
  float s = 0.f;
  for (int l=0;l<100;l++){
    float v = r[l];
    if (l==k) v += 1.0f;     // A = adj + I
    s += v;
  }
  dv[id] = 1.0f/sqrtf(s);
}

__global__ __launch_bounds__(256) void k_Ank(const float* __restrict__ padj, const float* __restrict__ dv,
                                             float* __restrict__ An){
  int id = blockIdx.x*256 + threadIdx.x;
  if (id >= NBG*10000) return;
  int b = id/10000;
  int rem = id - b*10000;
  int k = rem/100, l = rem - k*100;
  float a = padj[id] + ((k==l)? 1.0f : 0.0f);
  An[id] = (dv[b*100+k]*a)*dv[b*100+l];
}

__global__ __launch_bounds__(256) void k_y2(const float* __restrict__ An, const float* __restrict__ h,
    const float* __restrict__ bias, float* __restrict__ y){
  int id = blockIdx.x*256 + threadIdx.x;
  if (id >= NBG*100*30) return;
  int d = id % 30;
  int bk = id / 30;
  int b = bk / 100;
  const float* Ar = An + bk*100;
  const float* hb = h + b*100*30;
  float acc = 0.f;
  for (int l=0;l<100;l++) acc += Ar[l]*hb[l*30+d];
  y[id] = acc + bias[d];
}

// ---------------- pools + FC ----------------
__global__ __launch_bounds__(64) void k_pool(const float* __restrict__ A, const float* __restrict__ Bv,
    const float* __restrict__ Cv, int rows, float* __restrict__ conv, int coff){
  int id = blockIdx.x*64 + threadIdx.x;
  if (id >= NBG*90) return;
  int b = id/90, j = id - b*90;
  const float* X = (j<30)? A : ((j<60)? Bv : Cv);
  int f = j % 30;
  const float* p = X + (b*rows)*30 + f;
  float m = -3.402823466e38f;
  for (int i=0;i<rows;i++) m = fmaxf(m, p[i*30]);
  conv[b*180 + coff + j] = m;
}

__global__ __launch_bounds__(64) void k_fc(const float* __restrict__ conv,
    const float* __restrict__ w1, const float* __restrict__ b1,
    const float* __restrict__ w2, const float* __restrict__ b2, float* __restrict__ out){
  __shared__ float row[180];
  __shared__ float hid[50];
  int b = blockIdx.x, t = threadIdx.x;
  for (int i=t;i<180;i+=64) row[i] = conv[b*180+i];
  __syncthreads();
  if (t < 50){
    float a = b1[t];
    for (int i=0;i<180;i++) a += row[i]*w1[i*50+t];
    hid[t] = fmaxf(a, 0.f);
  }
  __syncthreads();
  if (t < 6){
    float a = b2[t];
    for (int i=0;i<50;i++) a += hid[i]*w2[i*6+t];
    out[b*6+t] = a;
  }
  if (b==0 && t==63) out[NBG*6] = 0.0f;   // second tuple output: zeros((1,))
}

// ---------------------------------------------------------------------------
extern "C" void kernel_launch(void* const* d_in, const int* in_sizes, int n_in,
                              void* d_out, int out_size, void* d_ws, size_t ws_size,
                              hipStream_t stream)
{
  (void)in_sizes; (void)n_in; (void)out_size; (void)ws_size;
  const float* x   = (const float*)d_in[0];
  const int*   src = (const int*)d_in[1];
  const int*   dst = src + NEDGE;
  const float* w11=(const float*)d_in[3],  *b11=(const float*)d_in[4],  *g11=(const float*)d_in[5],  *be11=(const float*)d_in[6];
  const float* w12=(const float*)d_in[7],  *b12=(const float*)d_in[8],  *g12=(const float*)d_in[9],  *be12=(const float*)d_in[10];
  const float* w13=(const float*)d_in[11], *b13=(const float*)d_in[12], *g13=(const float*)d_in[13], *be13=(const float*)d_in[14];
  const float* w21=(const float*)d_in[15], *b21=(const float*)d_in[16], *g21=(const float*)d_in[17], *be21=(const float*)d_in[18];
  const float* w22=(const float*)d_in[19], *b22=(const float*)d_in[20], *g22=(const float*)d_in[21], *be22=(const float*)d_in[22];
  const float* w23=(const float*)d_in[23], *b23=(const float*)d_in[24], *g23=(const float*)d_in[25], *be23=(const float*)d_in[26];
  const float* betas=(const float*)d_in[27];
  const float* poolw=(const float*)d_in[28], *poolb=(const float*)d_in[29];
  const float* fc1w=(const float*)d_in[30], *fc1b=(const float*)d_in[31];
  const float* fc2w=(const float*)d_in[32], *fc2b=(const float*)d_in[33];
  float* out = (float*)d_out;

  uint8_t* basep = (uint8_t*)d_ws;
  size_t off = 0;
  auto take = [&](size_t bytes)->void*{
    void* p = basep + off;
    off = (off + bytes + 255) & ~(size_t)255;
    return p;
  };
  int* degi    = (int*)take((size_t)NN*4);
  int* dego    = (int*)take((size_t)NN*4);
  int* cntA    = (int*)take((size_t)NN*4);
  int* cntB    = (int*)take((size_t)NN*4);
  int* rp_in   = (int*)take((size_t)(NN+1)*4);
  int* rp_out  = (int*)take((size_t)(NN+1)*4);
  int* bsum    = (int*)take(256*4);
  int* col_in  = (int*)take((size_t)NEDGE*4);
  int* col_out = (int*)take((size_t)NEDGE*4);
  float* dinv  = (float*)take((size_t)NN*4);
  float* hbuf  = (float*)take((size_t)NN*30*4);
  float* tmpY  = (float*)take((size_t)NN*30*4);
  float* X1    = (float*)take((size_t)NN*30*4);
  float* X2    = (float*)take((size_t)NN*30*4);
  float* X3    = (float*)take((size_t)NN*30*4);
  float* bufA  = (float*)take((size_t)NN*126*4);
  float* bufB  = (float*)take((size_t)NN*126*4);
  float* partCS= (float*)take((size_t)6*256*64*4);
  float* fieldv= (float*)take(384*4);
  float* partBN= (float*)take(256*30*4);
  float* meanv = (float*)take(128);
  float* varv  = (float*)take(128);
  float* px    = (float*)take(192000*4);
  float* padj  = (float*)take(640000*4);
  float* An    = (float*)take(640000*4);
  float* dinv2 = (float*)take(6400*4);
  float* h2    = (float*)take(192000*4);
  float* y2    = (float*)take(192000*4);
  float* X21   = (float*)take(192000*4);
  float* X22   = (float*)take(192000*4);
  float* X23   = (float*)take(192000*4);
  float* conv  = (float*)take(64*180*4);

  // ---- CSR setup ----
  hipMemsetAsync(degi, 0, (size_t)NN*4, stream);
  hipMemsetAsync(dego, 0, (size_t)NN*4, stream);
  hipMemsetAsync(cntA, 0, (size_t)NN*4, stream);
  hipMemsetAsync(cntB, 0, (size_t)NN*4, stream);
  k_count<<<2048,256,0,stream>>>(src,dst,degi,dego);
  k_scan1<<<256,256,0,stream>>>(degi, rp_in, bsum);
  k_scan2<<<1,256,0,stream>>>(bsum);
  k_scan3<<<256,256,0,stream>>>(rp_in, bsum);
  k_scan1<<<256,256,0,stream>>>(dego, rp_out, bsum);
  k_scan2<<<1,256,0,stream>>>(bsum);
  k_scan3<<<256,256,0,stream>>>(rp_out, bsum);
  k_fill<<<2048,256,0,stream>>>(dst, rp_in, cntA, col_in);
  k_fill<<<2048,256,0,stream>>>(src, rp_out, cntB, col_out);
  k_sortrow<<<256,256,0,stream>>>(rp_in,  col_in,  src);
  k_sortrow<<<256,256,0,stream>>>(rp_out, col_out, dst);
  k_dinv<<<256,256,0,stream>>>(degi, dinv);

  auto run_bn = [&](const float* yin, float* xout, const float* g, const float* be, int nrow){
    k_bn_part<<<256,256,0,stream>>>(yin, nrow, meanv, 0, partBN);
    k_bn_red<<<1,32,0,stream>>>(partBN, (float)nrow, meanv);
    k_bn_part<<<256,256,0,stream>>>(yin, nrow, meanv, 1, partBN);
    k_bn_red<<<1,32,0,stream>>>(partBN, (float)nrow, varv);
    k_bn_apply<<<(nrow*30)/256,256,0,stream>>>(yin, meanv, varv, g, be, xout, nrow);
  };

  // ---- stage 1: sparse GCN + BN x3 ----
  k_mm30<3><<<7680,256,0,stream>>>(x, w11, hbuf, NN);
  k_gcn_agg<<<256,256,0,stream>>>(hbuf, rp_in, col_in, dinv, b11, tmpY);
  run_bn(tmpY, X1, g11, be11, NN);
  k_mm30<30><<<7680,256,0,stream>>>(X1, w12, hbuf, NN);
  k_gcn_agg<<<256,256,0,stream>>>(hbuf, rp_in, col_in, dinv, b12, tmpY);
  run_bn(tmpY, X2, g12, be12, NN);
  k_mm30<30><<<7680,256,0,stream>>>(X2, w13, hbuf, NN);
  k_gcn_agg<<<256,256,0,stream>>>(hbuf, rp_in, col_in, dinv, b13, tmpY);
  run_bn(tmpY, X3, g13, be13, NN);
  k_pool<<<90,64,0,stream>>>(X1, X2, X3, 1024, conv, 0);

  // ---- belief propagation: psi in per-run [NN][Q] layout, ping-pong A/B ----
  k_bp_first<<<1536,256,0,stream>>>(bufA);
  float* cur = bufA; float* nxt = bufB;
  for (int it=0; it<10; ++it){
    k_colsum_part<<<dim3(256,6),64,0,stream>>>(cur, partCS);
    k_field<<<1,384,0,stream>>>(partCS, betas, fieldv);
    int fin = (it==9);
    // final iter writes the [NN][126] concat into bufA (it8 psi there is dead)
    k_bp_step<<<1536,256,0,stream>>>(cur, nxt, bufA, rp_in, col_in, fieldv, betas, fin);
    float* tp = cur; cur = nxt; nxt = tp;
  }
  // final concatenated psi [NN][126] now in bufA

  // ---- diff-pool ----
  k_s1<<<2048,256,0,stream>>>(bufA, poolw, poolb, bufB);      // s1 [n,100] -> bufB
  k_T<<<256,256,0,stream>>>(bufB, rp_out, col_out, bufA);     // T = A*s1   -> bufA
  k_p1adj<<<1600,128,0,stream>>>(bufB, bufA, padj);
  k_p1x<<<1600,128,0,stream>>>(bufB, X3, px);
  k_dinv2<<<25,256,0,stream>>>(padj, dinv2);
  k_Ank<<<2500,256,0,stream>>>(padj, dinv2, An);

  // ---- stage 2: dense GCN + BN x3 ----
  auto gcn2 = [&](const float* xin, const float* w, const float* bb, const float* g,
                  const float* be, float* xout){
    k_mm30<30><<<750,256,0,stream>>>(xin, w, h2, NBG*100);
    k_y2<<<750,256,0,stream>>>(An, h2, bb, y2);
    run_bn(y2, xout, g, be, NBG*100);
  };
  gcn2(px,  w21, b21, g21, be21, X21);
  gcn2(X21, w22, b22, g22, be22, X22);
  gcn2(X22, w23, b23, g23, be23, X23);
  k_pool<<<90,64,0,stream>>>(X21, X22, X23, 100, conv, 90);

  // ---- FC head ----
  k_fc<<<64,64,0,stream>>>(conv, fc1w, fc1b, fc2w, fc2b, out);
}

// Round 3
// 3495.148 us; speedup vs baseline: 2.2393x; 2.2393x over previous
//
#include <hip/hip_runtime.h>
#include <stdint.h>

// ---------------------------------------------------------------------------
// Net_57604101374728: GCN(x3)+BN -> maxpool | 6x belief-prop -> diffpool ->
// dense GCN(x3)+BN -> maxpool -> FC. Full fp32 port of the JAX reference.
//
// R3: R1's thread-per-element BP (proven bit-exact, high occupancy) with a
// flat XCD-resident block mapping: block b -> XCD b%8 handles only graphs
// g == b%8 (mod 8), so each graph's psi slab stays in ONE XCD's L2
// (8 graphs x 516KB ~= 4MB L2). Init fused with first softmax. gcn_agg/k_T
// get the same mapping. FP op order identical to R1 (absmax was 0.0).
// ---------------------------------------------------------------------------

constexpr int NN    = 65536;    // total nodes
constexpr int NEDGE = 524288;   // edges
constexpr int NBG   = 64;       // graphs

__constant__ int cQS[6]   = {2,4,8,16,32,64};

// ---------------- threefry2x32 (20 rounds) ----------------
__device__ __forceinline__ void tf2x32(uint32_t k0, uint32_t k1, uint32_t x0, uint32_t x1,
                                       uint32_t& o0, uint32_t& o1){
  uint32_t ks[3] = {k0, k1, k0 ^ k1 ^ 0x1BD11BDAu};
  x0 += ks[0]; x1 += ks[1];
  const int RA[4] = {13,15,26,6}, RB[4] = {17,29,16,24};
  #pragma unroll
  for (int i=0;i<5;i++){
    const int* r = (i&1)? RB : RA;
    #pragma unroll
    for (int j=0;j<4;j++){
      x0 += x1;
      x1 = (x1 << r[j]) | (x1 >> (32 - r[j]));
      x1 ^= x0;
    }
    x0 += ks[(i+1)%3];
    x1 += ks[(i+2)%3] + (uint32_t)(i+1);
  }
  o0 = x0; o1 = x1;
}

// ---------------- XLA ErfInv32 (Giles), contraction off ----------------
__device__ __forceinline__ float erfinv32(float xx){
  #pragma clang fp contract(off)
  float w = -log1pf(-xx*xx);
  float p;
  if (w < 5.0f){
    w = w - 2.5f;
    p = 2.81022636e-08f;
    p = 3.43273939e-07f  + p*w;
    p = -3.5233877e-06f  + p*w;
    p = -4.39150654e-06f + p*w;
    p = 0.00021858087f   + p*w;
    p = -0.00125372503f  + p*w;
    p = -0.00417768164f  + p*w;
    p = 0.246640727f     + p*w;
    p = 1.50140941f      + p*w;
  } else {
    w = sqrtf(w) - 3.0f;
    p = -0.000200214257f;
    p = 0.000100950558f  + p*w;
    p = 0.00134934322f   + p*w;
    p = -0.00367342844f  + p*w;
    p = 0.00573950773f   + p*w;
    p = -0.0076224613f   + p*w;
    p = 0.00943887047f   + p*w;
    p = 1.00167406f      + p*w;
    p = 2.83297682f      + p*w;
  }
  return p*xx;
}

// ---------------- CSR construction ----------------
__global__ __launch_bounds__(256) void k_count(const int* __restrict__ src, const int* __restrict__ dst,
                                               int* __restrict__ degi, int* __restrict__ dego){
  int e = blockIdx.x*256 + threadIdx.x;
  if (e >= NEDGE) return;
  atomicAdd(&degi[dst[e]], 1);
  atomicAdd(&dego[src[e]], 1);
}

__global__ __launch_bounds__(256) void k_scan1(const int* __restrict__ deg, int* __restrict__ rp,
                                               int* __restrict__ bsum){
  __shared__ int lds[256];
  int b = blockIdx.x, t = threadIdx.x;
  lds[t] = deg[b*256 + t];
  __syncthreads();
  for (int s=1;s<256;s<<=1){
    int add = (t>=s)? lds[t-s] : 0;
    __syncthreads();
    lds[t] += add;
    __syncthreads();
  }
  rp[b*256 + t + 1] = lds[t];
  if (t==0 && b==0) rp[0] = 0;
  if (t==255) bsum[b] = lds[255];
}

__global__ __launch_bounds__(256) void k_scan2(int* __restrict__ bsum){
  __shared__ int lds[256];
  int t = threadIdx.x;
  lds[t] = bsum[t];
  __syncthreads();
  for (int s=1;s<256;s<<=1){
    int add = (t>=s)? lds[t-s] : 0;
    __syncthreads();
    lds[t] += add;
    __syncthreads();
  }
  bsum[t] = (t==0)? 0 : lds[t-1];
}

__global__ __launch_bounds__(256) void k_scan3(int* __restrict__ rp, const int* __restrict__ bsum){
  int b = blockIdx.x, t = threadIdx.x;
  rp[b*256 + t + 1] += bsum[b];
}

__global__ __launch_bounds__(256) void k_fill(const int* __restrict__ key, const int* __restrict__ rp,
                                              int* __restrict__ cnt, int* __restrict__ colbuf){
  int e = blockIdx.x*256 + threadIdx.x;
  if (e >= NEDGE) return;
  int d = key[e];
  int p = atomicAdd(&cnt[d], 1);
  colbuf[rp[d] + p] = e;             // store edge id (sorted next for determinism)
}

__global__ __launch_bounds__(256) void k_sortrow(const int* __restrict__ rp, int* __restrict__ colbuf,
                                                 const int* __restrict__ other){
  int v = blockIdx.x*256 + threadIdx.x;
  if (v >= NN) return;
  int s0 = rp[v], s1 = rp[v+1];
  for (int i=s0+1;i<s1;i++){         // insertion sort by edge id ascending
    int key = colbuf[i]; int j = i-1;
    while (j>=s0 && colbuf[j]>key){ colbuf[j+1]=colbuf[j]; j--; }
    colbuf[j+1] = key;
  }
  for (int i=s0;i<s1;i++) colbuf[i] = other[colbuf[i]];
}

__global__ __launch_bounds__(256) void k_dinv(const int* __restrict__ degi, float* __restrict__ dinv){
  int v = blockIdx.x*256 + threadIdx.x;
  if (v >= NN) return;
  dinv[v] = 1.0f / sqrtf((float)(degi[v] + 1));   // +1 for self loop
}

// ---------------- stage-1 GCN ----------------
template<int CIN>
__global__ __launch_bounds__(256) void k_mm30(const float* __restrict__ x, const float* __restrict__ w,
                                              float* __restrict__ h, int nrow){
  __shared__ float ws[CIN*30];
  int t = threadIdx.x;
  for (int i=t;i<CIN*30;i+=256) ws[i] = w[i];
  __syncthreads();
  int id = blockIdx.x*256 + t;
  if (id >= nrow*30) return;
  int v = id/30, j = id - v*30;
  const float* xr = x + v*CIN;
  float acc = 0.f;
  #pragma unroll
  for (int k=0;k<CIN;k++) acc += xr[k]*ws[k*30+j];
  h[id] = acc;
}

// thread-per-element (R1 form) + XCD-resident graph mapping. 120 blocks/graph.
__global__ __launch_bounds__(256) void k_gcn_agg(const float* __restrict__ h, const int* __restrict__ rp,
    const int* __restrict__ col, const float* __restrict__ dinv, const float* __restrict__ bias,
    float* __restrict__ y){
  int b = blockIdx.x;
  int xcd = b & 7, i = b >> 3;       // 960 per xcd
  int gs = i/120, j = i - gs*120;
  int graph = gs*8 + xcd;
  int id = graph*30720 + j*256 + threadIdx.x;
  int v = id/30, jc = id - v*30;
  float dv = dinv[v];
  float acc = 0.f;
  int a = rp[v], e = rp[v+1];
  for (int k=a;k<e;k++){
    int s = col[k];
    acc += h[s*30 + jc] * (dinv[s]*dv);
  }
  acc += h[id]*(dv*dv);      // self loop appended last (matches JAX concat order)
  y[id] = acc + bias[jc];
}

// ---------------- BatchNorm (two-pass, biased var) ----------------
__global__ __launch_bounds__(256) void k_bn_part(const float* __restrict__ x, int nrow,
    const float* __restrict__ mean, int pass, float* __restrict__ part){
  __shared__ float lds[256*31];
  int b = blockIdx.x, t = threadIdx.x;
  int rows = nrow >> 8;              // rows per block (nrow divisible by 256)
  float acc[30];
  #pragma unroll
  for (int f=0;f<30;f++) acc[f] = 0.f;
  for (int r=t; r<rows; r+=256){
    const float* xr = x + (b*rows + r)*30;
    if (pass == 0){
      #pragma unroll
      for (int f=0;f<30;f++) acc[f] += xr[f];
    } else {
      #pragma unroll
      for (int f=0;f<30;f++){ float d = xr[f]-mean[f]; acc[f] += d*d; }
    }
  }
  #pragma unroll
  for (int f=0;f<30;f++) lds[t*31+f] = acc[f];
  __syncthreads();
  for (int s=128;s>0;s>>=1){
    if (t<s){
      #pragma unroll
      for (int f=0;f<30;f++) lds[t*31+f] += lds[(t+s)*31+f];
    }
    __syncthreads();
  }
  if (t<30) part[b*30+t] = lds[t];
}

__global__ void k_bn_red(const float* __restrict__ part, float n, float* __restrict__ out){
  int f = threadIdx.x;
  if (f >= 30) return;
  float s = 0.f;
  for (int b=0;b<256;b++) s += part[b*30+f];
  out[f] = s / n;
}

__global__ __launch_bounds__(256) void k_bn_apply(const float* __restrict__ x, const float* __restrict__ mean,
    const float* __restrict__ var, const float* __restrict__ g, const float* __restrict__ be,
    float* __restrict__ out, int nrow){
  int id = blockIdx.x*256 + threadIdx.x;
  if (id >= nrow*30) return;
  int f = id % 30;
  out[id] = g[f]*(x[id]-mean[f]) * (1.0f/sqrtf(var[f]+1e-5f)) + be[f];
}

// ---------------- belief propagation (thread-per-element, XCD-resident) ----
// Flat block map: 504 blocks/graph (runs: 8,16,32,64,128,256 blocks), 8
// graphs/XCD, 32256 blocks total. Decode run from within-graph block id.
__device__ __forceinline__ void bp_decode(int b, int& graph, int& run, int& jj){
  int xcd = b & 7, i = b >> 3;
  int gs = i/504, j = i - gs*504;
  if      (j <   8){ run=0; jj=j;     }
  else if (j <  24){ run=1; jj=j-8;   }
  else if (j <  56){ run=2; jj=j-24;  }
  else if (j < 120){ run=3; jj=j-56;  }
  else if (j < 248){ run=4; jj=j-120; }
  else             { run=5; jj=j-248; }
  graph = gs*8 + xcd;
}

template<int Q, int CO, int L2Q>
__device__ __forceinline__ void bp_first_elem(int graph, int jj, float* __restrict__ psi,
                                              uint32_t k0, uint32_t k1){
  int elem = jj*256 + threadIdx.x;          // [0, 1024*Q)
  int rg = elem >> L2Q, c = elem & (Q-1);
  int row = graph*1024 + rg;
  uint32_t b0, b1;
  tf2x32(k0, k1, 0u, (uint32_t)(row*Q + c), b0, b1);   // counter = (0, idx)
  uint32_t bits = b0 ^ b1;
  float f = __uint_as_float((bits>>9) | 0x3F800000u) - 1.0f;     // [0,1)
  const float lo = __uint_as_float(0xBF7FFFFFu);                 // nextafter(-1,0)
  float u = fmaxf(lo, f*2.0f + lo);
  float v = __uint_as_float(0x3FB504F3u) * erfinv32(u);          // sqrt(2)*erfinv
  // softmax over q-lane group (same shuffle sequence as R1)
  float m = v;
  #pragma unroll
  for (int off=Q>>1; off; off>>=1) m = fmaxf(m, __shfl_xor(m, off, Q));
  float e = expf(v - m);
  float ss = e;
  #pragma unroll
  for (int off=Q>>1; off; off>>=1) ss += __shfl_xor(ss, off, Q);
  psi[row*126 + CO + c] = e / ss;
}

__global__ __launch_bounds__(256) void k_bp_first(float* __restrict__ psi){
  int graph, run, jj;
  bp_decode(blockIdx.x, graph, run, jj);
  uint32_t k0, k1;
  tf2x32(0u, 42u, 0u, (uint32_t)run, k0, k1);          // fold_in(key(42), run)
  switch(run){
    case 0: bp_first_elem< 2, 0,1>(graph, jj, psi, k0, k1); break;
    case 1: bp_first_elem< 4, 2,2>(graph, jj, psi, k0, k1); break;
    case 2: bp_first_elem< 8, 6,3>(graph, jj, psi, k0, k1); break;
    case 3: bp_first_elem<16,14,4>(graph, jj, psi, k0, k1); break;
    case 4: bp_first_elem<32,30,5>(graph, jj, psi, k0, k1); break;
    default:bp_first_elem<64,62,6>(graph, jj, psi, k0, k1); break;
  }
}

template<int Q, int CO, int L2Q>
__device__ __forceinline__ void bp_step_elem(int graph, int run, int jj,
    const float* __restrict__ cur, float* __restrict__ nxt,
    const int* __restrict__ rp, const int* __restrict__ col,
    const float* __restrict__ field, float eb){
  int elem = jj*256 + threadIdx.x;
  int rg = elem >> L2Q, c = elem & (Q-1);
  int row = graph*1024 + rg;
  float acc = 0.f;
  int a = rp[row], b2 = rp[row+1];
  for (int i=a;i<b2;i++){
    int s = col[i];
    acc += log1pf(eb * cur[s*126 + CO + c]);
  }
  float v = acc - field[run*64 + c];
  float m = v;
  #pragma unroll
  for (int off=Q>>1; off; off>>=1) m = fmaxf(m, __shfl_xor(m, off, Q));
  float e = expf(v - m);
  float ss = e;
  #pragma unroll
  for (int off=Q>>1; off; off>>=1) ss += __shfl_xor(ss, off, Q);
  nxt[row*126 + CO + c] = e / ss;
}

__global__ __launch_bounds__(256) void k_bp_step(const float* __restrict__ cur,
    float* __restrict__ nxt, const int* __restrict__ rp, const int* __restrict__ col,
    const float* __restrict__ field, const float* __restrict__ betas){
  int graph, run, jj;
  bp_decode(blockIdx.x, graph, run, jj);
  float eb = expm1f(betas[run]);
  switch(run){
    case 0: bp_step_elem< 2, 0,1>(graph, run, jj, cur, nxt, rp, col, field, eb); break;
    case 1: bp_step_elem< 4, 2,2>(graph, run, jj, cur, nxt, rp, col, field, eb); break;
    case 2: bp_step_elem< 8, 6,3>(graph, run, jj, cur, nxt, rp, col, field, eb); break;
    case 3: bp_step_elem<16,14,4>(graph, run, jj, cur, nxt, rp, col, field, eb); break;
    case 4: bp_step_elem<32,30,5>(graph, run, jj, cur, nxt, rp, col, field, eb); break;
    default:bp_step_elem<64,62,6>(graph, run, jj, cur, nxt, rp, col, field, eb); break;
  }
}

// column sums, sequential row order within 256-row chunks (order == R1);
// XCD-resident: block b -> xcd b%8, graphs g == xcd (mod 8). 1536 blocks x64.
__global__ __launch_bounds__(64) void k_colsum_part(const float* __restrict__ cur, float* __restrict__ part){
  int b = blockIdx.x;
  int xcd = b & 7, i = b >> 3;       // i in [0,192)
  int gs = i/24, rem = i - gs*24;
  int run = rem >> 2, cg = rem & 3;
  int graph = gs*8 + xcd;
  int chunk = graph*4 + cg;          // global 256-row chunk id (== R1 "b")
  int q = cQS[run];
  int co = (run==0)?0:(run==1)?2:(run==2)?6:(run==3)?14:(run==4)?30:62;
  int c = threadIdx.x;
  if (c >= q) return;
  float s = 0.f;
  const float* p = cur + (size_t)chunk*256*126 + co + c;
  for (int r=0;r<256;r++) s += p[r*126];
  part[(run*256 + chunk)*64 + c] = s;
}

__global__ void k_field(const float* __restrict__ part, const float* __restrict__ betas,
                        float* __restrict__ field){
  int id = threadIdx.x;              // 384 threads: 6 runs x 64 cols
  int run = id >> 6, c = id & 63;
  if (c >= cQS[run]) return;
  float s = 0.f;
  for (int b=0;b<256;b++) s += part[(run*256 + b)*64 + c];
  float beta = betas[run];
  field[id] = s * (3.8f*beta/65536.0f);
}

// ---------------- diff-pool ----------------
__global__ __launch_bounds__(256) void k_s1(const float* __restrict__ cat, const float* __restrict__ pw,
                                            const float* __restrict__ pb, float* __restrict__ s1){
  __shared__ float wl[12600];
  __shared__ float rowb[2][126];
  __shared__ float red[8];
  int t = threadIdx.x;
  for (int i=t;i<12600;i+=256) wl[i] = pw[i];
  int half = t>>7, tl = t&127, wid = t>>6;
  __syncthreads();
  for (int it=0; it<16; ++it){
    int v = blockIdx.x*32 + it*2 + half;
    if (tl < 126) rowb[half][tl] = cat[v*126 + tl];
    __syncthreads();
    float acc = -3.402823466e38f;
    if (tl < 100){
      acc = pb[tl];
      for (int j=0;j<126;j++) acc += rowb[half][j]*wl[j*100+tl];
    }
    float m = acc;
    for (int off=32; off; off>>=1) m = fmaxf(m, __shfl_xor(m, off, 64));
    if ((t&63)==0) red[wid] = m;
    __syncthreads();
    m = fmaxf(red[half*2], red[half*2+1]);
    float e = (tl<100)? expf(acc - m) : 0.f;
    float ss = e;
    for (int off=32; off; off>>=1) ss += __shfl_xor(ss, off, 64);
    if ((t&63)==0) red[4+wid] = ss;
    __syncthreads();
    float stot = red[4+half*2] + red[4+half*2+1];
    if (tl<100) s1[v*100+tl] = e/stot;
    __syncthreads();
  }
}

// thread-per-element (R1 form) + XCD mapping. 400 blocks/graph.
__global__ __launch_bounds__(256) void k_T(const float* __restrict__ s1, const int* __restrict__ rp,
                                           const int* __restrict__ col, float* __restrict__ T){
  int b = blockIdx.x;
  int xcd = b & 7, i = b >> 3;       // 3200 per xcd
  int gs = i/400, j = i - gs*400;
  int graph = gs*8 + xcd;
  int id = graph*102400 + j*256 + threadIdx.x;
  int v = id/100, l = id - v*100;
  float acc = 0.f;
  int a = rp[v], e = rp[v+1];
  for (int k=a;k<e;k++) acc += s1[col[k]*100 + l];
  T[id] = acc;
}

__global__ __launch_bounds__(128) void k_p1adj(const float* __restrict__ s1, const float* __restrict__ T,
                                               float* __restrict__ padj){
  int b  = blockIdx.x/25;
  int k0 = (blockIdx.x%25)*4;
  int l  = threadIdx.x;
  const float* s1b = s1 + b*1024*100;
  const float* Tb  = T  + b*1024*100;
  float a0=0.f,a1=0.f,a2=0.f,a3=0.f;
  for (int n=0;n<1024;n++){
    float tv = (l<100)? Tb[n*100+l] : 0.f;
    const float* sr = s1b + n*100 + k0;
    a0 += sr[0]*tv; a1 += sr[1]*tv; a2 += sr[2]*tv; a3 += sr[3]*tv;
  }
  if (l<100){
    float* o = padj + b*10000 + k0*100 + l;
    o[0]=a0; o[100]=a1; o[200]=a2; o[300]=a3;
  }
}

__global__ __launch_bounds__(128) void k_p1x(const float* __restrict__ s1, const float* __restrict__ x13,
                                             float* __restrict__ px){
  int b  = blockIdx.x/25;
  int k0 = (blockIdx.x%25)*4;
  int t = threadIdx.x;
  int j = t>>5, d = t&31;
  float acc = 0.f;
  for (int n=0;n<1024;n++){
    float xv = (d<30)? x13[(b*1024+n)*30 + d] : 0.f;
    acc += s1[(b*1024+n)*100 + k0 + j]*xv;
  }
  if (d<30) px[(b*100 + k0 + j)*30 + d] = acc;
}

// ---------------- stage-2 dense GCN ----------------
__global__ __launch_bounds__(256) void k_dinv2(const float* __restrict__ padj, float* __restrict__ dv){
  int id = blockIdx.x*256 + threadIdx.x;
  if (id >= NBG*100) return;
  const float* r = padj + id*100;
  int k = id % 100;
  float s = 0.f;
  for (int l=0;l<100;l++){
    float v = r[l];
    if (l==k) v += 1.0f;     // A = adj + I
    s += v;
  }
  dv[id] = 1.0f/sqrtf(s);
}

__global__ __launch_bounds__(256) void k_Ank(const float* __restrict__ padj, const float* __restrict__ dv,
                                             float* __restrict__ An){
  int id = blockIdx.x*256 + threadIdx.x;
  if (id >= NBG*10000) return;
  int b = id/10000;
  int rem = id - b*10000;
  int k = rem/100, l = rem - k*100;
  float a = padj[id] + ((k==l)? 1.0f : 0.0f);
  An[id] = (dv[b*100+k]*a)*dv[b*100+l];
}

__global__ __launch_bounds__(256) void k_y2(const float* __restrict__ An, const float* __restrict__ h,
    const float* __restrict__ bias, float* __restrict__ y){
  int id = blockIdx.x*256 + threadIdx.x;
  if (id >= NBG*100*30) return;
  int d = id % 30;
  int bk = id / 30;
  int b = bk / 100;
  const float* Ar = An + bk*100;
  const float* hb = h + b*100*30;
  float acc = 0.f;
  for (int l=0;l<100;l++) acc += Ar[l]*hb[l*30+d];
  y[id] = acc + bias[d];
}

// ---------------- pools + FC ----------------
__global__ __launch_bounds__(64) void k_pool(const float* __restrict__ A, const float* __restrict__ Bv,
    const float* __restrict__ Cv, int rows, float* __restrict__ conv, int coff){
  int id = blockIdx.x*64 + threadIdx.x;
  if (id >= NBG*90) return;
  int b = id/90, j = id - b*90;
  const float* X = (j<30)? A : ((j<60)? Bv : Cv);
  int f = j % 30;
  const float* p = X + (b*rows)*30 + f;
  float m = -3.402823466e38f;
  for (int i=0;i<rows;i++) m = fmaxf(m, p[i*30]);
  conv[b*180 + coff + j] = m;
}

__global__ __launch_bounds__(64) void k_fc(const float* __restrict__ conv,
    const float* __restrict__ w1, const float* __restrict__ b1,
    const float* __restrict__ w2, const float* __restrict__ b2, float* __restrict__ out){
  __shared__ float row[180];
  __shared__ float hid[50];
  int b = blockIdx.x, t = threadIdx.x;
  for (int i=t;i<180;i+=64) row[i] = conv[b*180+i];
  __syncthreads();
  if (t < 50){
    float a = b1[t];
    for (int i=0;i<180;i++) a += row[i]*w1[i*50+t];
    hid[t] = fmaxf(a, 0.f);
  }
  __syncthreads();
  if (t < 6){
    float a = b2[t];
    for (int i=0;i<50;i++) a += hid[i]*w2[i*6+t];
    out[b*6+t] = a;
  }
  if (b==0 && t==63) out[NBG*6] = 0.0f;   // second tuple output: zeros((1,))
}

// ---------------------------------------------------------------------------
extern "C" void kernel_launch(void* const* d_in, const int* in_sizes, int n_in,
                              void* d_out, int out_size, void* d_ws, size_t ws_size,
                              hipStream_t stream)
{
  (void)in_sizes; (void)n_in; (void)out_size; (void)ws_size;
  const float* x   = (const float*)d_in[0];
  const int*   src = (const int*)d_in[1];
  const int*   dst = src + NEDGE;
  const float* w11=(const float*)d_in[3],  *b11=(const float*)d_in[4],  *g11=(const float*)d_in[5],  *be11=(const float*)d_in[6];
  const float* w12=(const float*)d_in[7],  *b12=(const float*)d_in[8],  *g12=(const float*)d_in[9],  *be12=(const float*)d_in[10];
  const float* w13=(const float*)d_in[11], *b13=(const float*)d_in[12], *g13=(const float*)d_in[13], *be13=(const float*)d_in[14];
  const float* w21=(const float*)d_in[15], *b21=(const float*)d_in[16], *g21=(const float*)d_in[17], *be21=(const float*)d_in[18];
  const float* w22=(const float*)d_in[19], *b22=(const float*)d_in[20], *g22=(const float*)d_in[21], *be22=(const float*)d_in[22];
  const float* w23=(const float*)d_in[23], *b23=(const float*)d_in[24], *g23=(const float*)d_in[25], *be23=(const float*)d_in[26];
  const float* betas=(const float*)d_in[27];
  const float* poolw=(const float*)d_in[28], *poolb=(const float*)d_in[29];
  const float* fc1w=(const float*)d_in[30], *fc1b=(const float*)d_in[31];
  const float* fc2w=(const float*)d_in[32], *fc2b=(const float*)d_in[33];
  float* out = (float*)d_out;

  uint8_t* basep = (uint8_t*)d_ws;
  size_t off = 0;
  auto take = [&](size_t bytes)->void*{
    void* p = basep + off;
    off = (off + bytes + 255) & ~(size_t)255;
    return p;
  };
  int* degi    = (int*)take((size_t)NN*4);
  int* dego    = (int*)take((size_t)NN*4);
  int* cntA    = (int*)take((size_t)NN*4);
  int* cntB    = (int*)take((size_t)NN*4);
  int* rp_in   = (int*)take((size_t)(NN+1)*4);
  int* rp_out  = (int*)take((size_t)(NN+1)*4);
  int* bsum    = (int*)take(256*4);
  int* col_in  = (int*)take((size_t)NEDGE*4);
  int* col_out = (int*)take((size_t)NEDGE*4);
  float* dinv  = (float*)take((size_t)NN*4);
  float* hbuf  = (float*)take((size_t)NN*30*4);
  float* tmpY  = (float*)take((size_t)NN*30*4);
  float* X1    = (float*)take((size_t)NN*30*4);
  float* X2    = (float*)take((size_t)NN*30*4);
  float* X3    = (float*)take((size_t)NN*30*4);
  float* bufA  = (float*)take((size_t)NN*126*4);
  float* bufB  = (float*)take((size_t)NN*126*4);
  float* partCS= (float*)take((size_t)6*256*64*4);
  float* fieldv= (float*)take(384*4);
  float* partBN= (float*)take(256*30*4);
  float* meanv = (float*)take(128);
  float* varv  = (float*)take(128);
  float* px    = (float*)take(192000*4);
  float* padj  = (float*)take(640000*4);
  float* An    = (float*)take(640000*4);
  float* dinv2 = (float*)take(6400*4);
  float* h2    = (float*)take(192000*4);
  float* y2    = (float*)take(192000*4);
  float* X21   = (float*)take(192000*4);
  float* X22   = (float*)take(192000*4);
  float* X23   = (float*)take(192000*4);
  float* conv  = (float*)take(64*180*4);

  // ---- CSR setup ----
  hipMemsetAsync(degi, 0, (size_t)NN*4, stream);
  hipMemsetAsync(dego, 0, (size_t)NN*4, stream);
  hipMemsetAsync(cntA, 0, (size_t)NN*4, stream);
  hipMemsetAsync(cntB, 0, (size_t)NN*4, stream);
  k_count<<<2048,256,0,stream>>>(src,dst,degi,dego);
  k_scan1<<<256,256,0,stream>>>(degi, rp_in, bsum);
  k_scan2<<<1,256,0,stream>>>(bsum);
  k_scan3<<<256,256,0,stream>>>(rp_in, bsum);
  k_scan1<<<256,256,0,stream>>>(dego, rp_out, bsum);
  k_scan2<<<1,256,0,stream>>>(bsum);
  k_scan3<<<256,256,0,stream>>>(rp_out, bsum);
  k_fill<<<2048,256,0,stream>>>(dst, rp_in, cntA, col_in);
  k_fill<<<2048,256,0,stream>>>(src, rp_out, cntB, col_out);
  k_sortrow<<<256,256,0,stream>>>(rp_in,  col_in,  src);
  k_sortrow<<<256,256,0,stream>>>(rp_out, col_out, dst);
  k_dinv<<<256,256,0,stream>>>(degi, dinv);

  auto run_bn = [&](const float* yin, float* xout, const float* g, const float* be, int nrow){
    k_bn_part<<<256,256,0,stream>>>(yin, nrow, meanv, 0, partBN);
    k_bn_red<<<1,32,0,stream>>>(partBN, (float)nrow, meanv);
    k_bn_part<<<256,256,0,stream>>>(yin, nrow, meanv, 1, partBN);
    k_bn_red<<<1,32,0,stream>>>(partBN, (float)nrow, varv);
    k_bn_apply<<<(nrow*30)/256,256,0,stream>>>(yin, meanv, varv, g, be, xout, nrow);
  };

  // ---- stage 1: sparse GCN + BN x3 ----
  k_mm30<3><<<7680,256,0,stream>>>(x, w11, hbuf, NN);
  k_gcn_agg<<<7680,256,0,stream>>>(hbuf, rp_in, col_in, dinv, b11, tmpY);
  run_bn(tmpY, X1, g11, be11, NN);
  k_mm30<30><<<7680,256,0,stream>>>(X1, w12, hbuf, NN);
  k_gcn_agg<<<7680,256,0,stream>>>(hbuf, rp_in, col_in, dinv, b12, tmpY);
  run_bn(tmpY, X2, g12, be12, NN);
  k_mm30<30><<<7680,256,0,stream>>>(X2, w13, hbuf, NN);
  k_gcn_agg<<<7680,256,0,stream>>>(hbuf, rp_in, col_in, dinv, b13, tmpY);
  run_bn(tmpY, X3, g13, be13, NN);
  k_pool<<<90,64,0,stream>>>(X1, X2, X3, 1024, conv, 0);

  // ---- belief propagation ([NN][126] layout, ping-pong A/B) ----
  k_bp_first<<<32256,256,0,stream>>>(bufA);
  float* cur = bufA; float* nxt = bufB;
  for (int it=0; it<10; ++it){
    k_colsum_part<<<1536,64,0,stream>>>(cur, partCS);
    k_field<<<1,384,0,stream>>>(partCS, betas, fieldv);
    k_bp_step<<<32256,256,0,stream>>>(cur, nxt, rp_in, col_in, fieldv, betas);
    float* tp = cur; cur = nxt; nxt = tp;
  }
  // final concatenated psi [NN][126] now in bufA (10 swaps -> back to bufA)

  // ---- diff-pool ----
  k_s1<<<2048,256,0,stream>>>(bufA, poolw, poolb, bufB);      // s1 [n,100] -> bufB
  k_T<<<25600,256,0,stream>>>(bufB, rp_out, col_out, bufA);   // T = A*s1   -> bufA
  k_p1adj<<<1600,128,0,stream>>>(bufB, bufA, padj);
  k_p1x<<<1600,128,0,stream>>>(bufB, X3, px);
  k_dinv2<<<25,256,0,stream>>>(padj, dinv2);
  k_Ank<<<2500,256,0,stream>>>(padj, dinv2, An);

  // ---- stage 2: dense GCN + BN x3 ----
  auto gcn2 = [&](const float* xin, const float* w, const float* bb, const float* g,
                  const float* be, float* xout){
    k_mm30<30><<<750,256,0,stream>>>(xin, w, h2, NBG*100);
    k_y2<<<750,256,0,stream>>>(An, h2, bb, y2);
    run_bn(y2, xout, g, be, NBG*100);
  };
  gcn2(px,  w21, b21, g21, be21, X21);
  gcn2(X21, w22, b22, g22, be22, X22);
  gcn2(X22, w23, b23, g23, be23, X23);
  k_pool<<<90,64,0,stream>>>(X21, X22, X23, 100, conv, 90);

  // ---- FC head ----
  k_fc<<<64,64,0,stream>>>(conv, fc1w, fc1b, fc2w, fc2b, out);
}